// Round 12
// baseline (1939.159 us; speedup 1.0000x reference)
//
#include <hip/hip_runtime.h>
#include <cstdint>
#include <cstddef>

#define NB_TOT 1024
#define NANT 64
#define MM 16
#define MPAD 17   // odd stride: strided LDS access hits all 32 banks (conflict-free)
#define DA 4096
#define MAXIT 20
#define SPB 4     // samples per block
#define NTHR 1024 // 16 waves
#define JCOLS 4   // consecutive cols per thread: a = tid*4 + j
#define L_CONST 10.0f

__global__ __launch_bounds__(NTHR)
__attribute__((amdgpu_waves_per_eu(4, 4)))   // pin 4 waves/SIMD => VGPR budget 128, no spill-for-occupancy
void mpnet_kernel(const float* __restrict__ x_re, const float* __restrict__ x_im,
                  const float* __restrict__ xm_re, const float* __restrict__ xm_im,
                  const float* __restrict__ M_re, const float* __restrict__ M_im,
                  const float* __restrict__ W_re, const float* __restrict__ W_im,
                  const float* __restrict__ sigma,
                  float* __restrict__ out, int outn_i)
{
  __shared__ float Msh_re[SPB][NANT][MPAD];   // 17.4 KB
  __shared__ float Msh_im[SPB][NANT][MPAD];   // 17.4 KB
  __shared__ float tsh[NANT][8];              // 2 KB, 32B rows (float4-aligned)
  __shared__ float einv_sh[DA];               // 16 KB
  __shared__ float rsd_re[SPB][MM], rsd_im[SPB][MM];
  __shared__ float resh_re[SPB][NANT], resh_im[SPB][NANT];
  __shared__ float red_c2[16][SPB];
  __shared__ int   red_ix[16][SPB];
  __shared__ int   sel_ix[SPB];
  __shared__ float sel_vr[SPB], sel_vi[SPB], sel_md[SPB];
  __shared__ float rn2_sh[SPB], thr_sh[SPB];
  __shared__ int   actsh[SPB];
  __shared__ int   any_act;

  const int tid = threadIdx.x;
  const int b0 = blockIdx.x * SPB;
  const size_t outn = (size_t)outn_i;

  // ---- init: stage M, residual(=x), res(=xm), thresholds
  for (int k2 = 0; k2 < 4; k2++){
    int idx = k2*NTHR + tid;            // 0..4095 = 4 samples x 64 n x 16 m
    int s = idx >> 10, rem = idx & 1023;
    int n = rem >> 4, m = rem & 15;
    Msh_re[s][n][m] = M_re[(size_t)b0*1024 + idx];
    Msh_im[s][n][m] = M_im[(size_t)b0*1024 + idx];
  }
  if (tid < SPB*MM){
    int s = tid >> 4, m = tid & 15;
    rsd_re[s][m] = x_re[(b0+s)*MM + m];
    rsd_im[s][m] = x_im[(b0+s)*MM + m];
  } else if (tid >= 64 && tid < 64 + SPB*NANT){
    int q = tid - 64, s = q >> 6, n = q & 63;
    resh_re[s][n] = xm_re[(b0+s)*NANT + n];
    resh_im[s][n] = xm_im[(b0+s)*NANT + n];
  } else if (tid >= 448 && tid < 448 + SPB){
    int s = tid - 448;
    float sg = sigma[b0+s];
    thr_sh[s] = ((sg*sg) * (float)NANT) * L_CONST;
    actsh[s] = 1;
  }

  // ---- phase 0: E column inverse norms (thread owns cols tid*4..+3)
  {
    float w2x=0.f, w2y=0.f, w2z=0.f, w2w=0.f;
    for (int n = 0; n < NANT; n++){
      float4 wr = *(const float4*)(W_re + (size_t)n*DA + (tid<<2));
      float4 wi = *(const float4*)(W_im + (size_t)n*DA + (tid<<2));
      w2x += wr.x*wr.x + wi.x*wi.x;
      w2y += wr.y*wr.y + wi.y*wi.y;
      w2z += wr.z*wr.z + wi.z*wi.z;
      w2w += wr.w*wr.w + wi.w*wi.w;
    }
    einv_sh[(tid<<2)+0] = 1.f/sqrtf(w2x);
    einv_sh[(tid<<2)+1] = 1.f/sqrtf(w2y);
    einv_sh[(tid<<2)+2] = 1.f/sqrtf(w2z);
    einv_sh[(tid<<2)+3] = 1.f/sqrtf(w2w);
  }
  __syncthreads();

  // ---- phase 1: md = 1/||M_D col||; per sample, m in 2 chunks of 8 (scalar broadcast LDS reads)
  float md[SPB*JCOLS];   // md[s*4+j]
  #pragma unroll
  for (int s = 0; s < SPB; s++){
    float nrm[JCOLS];
    #pragma unroll
    for (int j = 0; j < JCOLS; j++) nrm[j] = 0.f;
    #pragma unroll
    for (int mc = 0; mc < 2; mc++){
      float cr[JCOLS][8], ci[JCOLS][8];
      #pragma unroll
      for (int j = 0; j < JCOLS; j++)
        #pragma unroll
        for (int q = 0; q < 8; q++){ cr[j][q]=0.f; ci[j][q]=0.f; }
      for (int n = 0; n < NANT; n++){
        float mrq[8], miq[8];
        #pragma unroll
        for (int q = 0; q < 8; q++){
          mrq[q] = Msh_re[s][n][mc*8+q];    // broadcast (all threads same addr) -> free
          miq[q] = Msh_im[s][n][mc*8+q];
        }
        float4 wr = *(const float4*)(W_re + (size_t)n*DA + (tid<<2));
        float4 wi = *(const float4*)(W_im + (size_t)n*DA + (tid<<2));
        float wrj[4] = {wr.x, wr.y, wr.z, wr.w};
        float wij[4] = {wi.x, wi.y, wi.z, wi.w};
        #pragma unroll
        for (int j = 0; j < JCOLS; j++){
          #pragma unroll
          for (int q = 0; q < 8; q++){
            cr[j][q] += mrq[q]*wrj[j] + miq[q]*wij[j];   // conj(M)*W
            ci[j][q] += mrq[q]*wij[j] - miq[q]*wrj[j];
          }
        }
      }
      #pragma unroll
      for (int j = 0; j < JCOLS; j++){
        float a = 0.f;
        #pragma unroll
        for (int q = 0; q < 8; q++) a += cr[j][q]*cr[j][q] + ci[j][q]*ci[j][q];
        nrm[j] += a;
      }
    }
    #pragma unroll
    for (int j = 0; j < JCOLS; j++) md[s*JCOLS+j] = 1.f/sqrtf(nrm[j]);
  }

  // ---- phase 2: 20 greedy iterations
  for (int it = 0; it < MAXIT; it++){
    // A: rn2 (tid<4), t = M.residual (tid 64..319), any_act=0 (tid 448)
    if (tid < SPB){
      float e = 0.f;
      for (int m = 0; m < MM; m++){
        float rr = rsd_re[tid][m], ri = rsd_im[tid][m];
        e += rr*rr + ri*ri;
      }
      rn2_sh[tid] = e;
    } else if (tid >= 64 && tid < 320){
      int q = tid - 64, s = q >> 6, n = q & 63;
      float tr = 0.f, ti = 0.f;
      #pragma unroll
      for (int m = 0; m < MM; m++){
        float mr = Msh_re[s][n][m], mi = Msh_im[s][n][m];
        float rr = rsd_re[s][m], ri = rsd_im[s][m];
        tr += mr*rr - mi*ri;          // t[n] = sum_m M[n,m]*r[m]
        ti += mr*ri + mi*rr;
      }
      tsh[n][2*s]   = tr;
      tsh[n][2*s+1] = ti;
    } else if (tid == 448){
      any_act = 0;
    }
    __syncthreads();
    if (tid < SPB){
      int a = (actsh[tid] && (rn2_sh[tid] >= thr_sh[tid])) ? 1 : 0;
      actsh[tid] = a;
      if (a) any_act = 1;
    }

    // B: g[s][j] = sum_n conj(W[n,a])*t[s,n], a = tid*4+j
    float gr[SPB][JCOLS], gi[SPB][JCOLS];
    #pragma unroll
    for (int s = 0; s < SPB; s++)
      #pragma unroll
      for (int j = 0; j < JCOLS; j++){ gr[s][j]=0.f; gi[s][j]=0.f; }
    for (int n = 0; n < NANT; n++){
      float4 t01 = *(const float4*)&tsh[n][0];   // t0r,t0i,t1r,t1i
      float4 t23 = *(const float4*)&tsh[n][4];   // t2r,t2i,t3r,t3i
      float4 wr = *(const float4*)(W_re + (size_t)n*DA + (tid<<2));
      float4 wi = *(const float4*)(W_im + (size_t)n*DA + (tid<<2));
      float wrj[4] = {wr.x, wr.y, wr.z, wr.w};
      float wij[4] = {wi.x, wi.y, wi.z, wi.w};
      float tr_[4] = {t01.x, t01.z, t23.x, t23.z};
      float ti_[4] = {t01.y, t01.w, t23.y, t23.w};
      #pragma unroll
      for (int s = 0; s < SPB; s++){
        #pragma unroll
        for (int j = 0; j < JCOLS; j++){
          gr[s][j] += wrj[j]*tr_[s] + wij[j]*ti_[s];
          gi[s][j] += wrj[j]*ti_[s] - wij[j]*tr_[s];
        }
      }
    }

    // C: per-thread best (max c2, min idx on tie)
    float bc2[SPB]; int bix[SPB];
    #pragma unroll
    for (int s = 0; s < SPB; s++){ bc2[s] = -1.f; bix[s] = 0; }
    #pragma unroll
    for (int j = 0; j < JCOLS; j++){
      int a = (tid<<2) + j;
      #pragma unroll
      for (int s = 0; s < SPB; s++){
        float mdv = md[s*JCOLS + j];
        float cre = gr[s][j]*mdv, cim = gi[s][j]*mdv;
        float c2 = cre*cre + cim*cim;
        if (c2 > bc2[s]){ bc2[s] = c2; bix[s] = a; }
      }
    }
    #pragma unroll
    for (int off = 32; off; off >>= 1){
      #pragma unroll
      for (int s = 0; s < SPB; s++){
        float oc2 = __shfl_down(bc2[s], off);
        int   oix = __shfl_down(bix[s], off);
        if (oc2 > bc2[s] || (oc2 == bc2[s] && oix < bix[s])){ bc2[s]=oc2; bix[s]=oix; }
      }
    }
    if ((tid & 63) == 0){
      int wid = tid >> 6;
      #pragma unroll
      for (int s = 0; s < SPB; s++){ red_c2[wid][s]=bc2[s]; red_ix[wid][s]=bix[s]; }
    }
    __syncthreads();
    if (!any_act) break;                 // uniform across block

    if (tid < SPB){
      float bc = red_c2[0][tid]; int bi = red_ix[0][tid];
      #pragma unroll
      for (int w = 1; w < 16; w++){
        float c = red_c2[w][tid]; int i2 = red_ix[w][tid];
        if (c > bc || (c == bc && i2 < bi)){ bc=c; bi=i2; }
      }
      sel_ix[tid] = bi;
    }
    __syncthreads();

    // D: owning thread publishes selected value (static g/md indexing)
    #pragma unroll
    for (int s = 0; s < SPB; s++){
      int I = sel_ix[s];
      if ((I >> 2) == tid){
        int jj = I & 3;
        #pragma unroll
        for (int j = 0; j < JCOLS; j++){
          if (jj == j){
            float mdv = md[s*JCOLS + j];
            sel_vr[s] = gr[s][j]*mdv;
            sel_vi[s] = gi[s][j]*mdv;
            sel_md[s] = mdv;
          }
        }
      }
    }
    __syncthreads();

    // E: updates, gated per-sample
    if (tid < 64){
      int s = tid >> 4, m = tid & 15;
      if (actsh[s]){
        int I = sel_ix[s];
        float vr = sel_vr[s], vi = sel_vi[s], mdv = sel_md[s];
        float cre = 0.f, cim = 0.f;
        for (int n = 0; n < NANT; n++){
          float mr = Msh_re[s][n][m], mi = Msh_im[s][n][m];
          float wr = W_re[(size_t)n*DA + I], wi = W_im[(size_t)n*DA + I];
          cre += mr*wr + mi*wi;        // conj(M)*W
          cim += mr*wi - mi*wr;
        }
        cre *= mdv; cim *= mdv;
        rsd_re[s][m] -= vr*cre - vi*cim;
        rsd_im[s][m] -= vr*cim + vi*cre;
      }
    } else if (tid >= 64 && tid < 320){
      int q = tid - 64, s = q >> 6, n = q & 63;
      if (actsh[s]){
        int I = sel_ix[s];
        float vr = sel_vr[s], vi = sel_vi[s];
        float wr = W_re[(size_t)n*DA + I], wi = W_im[(size_t)n*DA + I];
        float ei = einv_sh[I];
        float er = wr*ei, em = wi*ei;  // E[:,I]
        resh_re[s][n] -= vr*er - vi*em;
        resh_im[s][n] -= vr*em + vi*er;
      }
    }
    __syncthreads();
  }

  // ---- epilogue: f32, six planes: re parts first (res, xhat, xhm), then im parts
  if (tid < 64){
    int s = tid >> 4, m = tid & 15; int b = b0 + s;
    float rr = rsd_re[s][m], ri = rsd_im[s][m];
    size_t base = (size_t)b*MM + m;                 // 0..16383
    if (base < outn)          out[base]          = rr;                        // res.re
    if (16384 + base < outn)  out[16384 + base]  = x_re[b*MM+m] - rr;         // xhat.re
    if (98304 + base < outn)  out[98304 + base]  = ri;                        // res.im
    if (114688 + base < outn) out[114688 + base] = x_im[b*MM+m] - ri;         // xhat.im
  } else if (tid >= 64 && tid < 320){
    int q = tid - 64, s = q >> 6, n = q & 63; int b = b0 + s;
    size_t base = (size_t)b*NANT + n;               // 0..65535
    if (32768 + base < outn)  out[32768 + base]  = xm_re[b*NANT+n] - resh_re[s][n];  // xhm.re
    if (131072 + base < outn) out[131072 + base] = xm_im[b*NANT+n] - resh_im[s][n];  // xhm.im
  }
}

extern "C" void kernel_launch(void* const* d_in, const int* in_sizes, int n_in,
                              void* d_out, int out_size, void* d_ws, size_t ws_size,
                              hipStream_t stream) {
  (void)in_sizes; (void)n_in; (void)d_ws; (void)ws_size;
  const float* x_re  = (const float*)d_in[0];
  const float* x_im  = (const float*)d_in[1];
  const float* xm_re = (const float*)d_in[2];
  const float* xm_im = (const float*)d_in[3];
  const float* M_re  = (const float*)d_in[4];
  const float* M_im  = (const float*)d_in[5];
  const float* W_re  = (const float*)d_in[6];
  const float* W_im  = (const float*)d_in[7];
  const float* sig   = (const float*)d_in[8];
  float* out = (float*)d_out;

  dim3 grid(NB_TOT / SPB), block(NTHR);
  hipLaunchKernelGGL(mpnet_kernel, grid, block, 0, stream,
                     x_re, x_im, xm_re, xm_im, M_re, M_im, W_re, W_im,
                     sig, out, out_size);
}